// Round 4
// baseline (98.090 us; speedup 1.0000x reference)
//
#include <hip/hip_runtime.h>
#include <stdint.h>

#define NROWS 8192
#define HALF_N 4096
#define DIM 512          /* elements per row; == bytes per row in fp8 */
#define INV_TEMP 2.0f
#define E2SCALE 2.8853900817779268f  /* INV_TEMP * log2(e) */
#define LN2 0.6931471805599453f
#define NTILES 528       /* 256x256 tiles: 32*33/2 */
#define NXCD 8
#define TPX (NTILES / NXCD)  /* 66; NTILES % 8 == 0 so the swizzle is bijective */

typedef int i32x8 __attribute__((ext_vector_type(8)));
typedef float f32x16 __attribute__((ext_vector_type(16)));

// global -> LDS direct copy, 16B per lane; LDS dest is wave-uniform base + lane*16
__device__ __forceinline__ void gload_lds16(const unsigned char* g, unsigned char* l) {
  __builtin_amdgcn_global_load_lds(
      (const __attribute__((address_space(1))) unsigned int*)(uintptr_t)g,
      (__attribute__((address_space(3))) unsigned int*)(uint32_t)(uintptr_t)l,
      16, 0, 0);
}

// One wave per row: sumsq -> rsqrt -> fp8 e4m3 store (4 MB). Zeroes sumexp.
__global__ void __launch_bounds__(256) k_normalize(const float* __restrict__ zi,
                                                   const float* __restrict__ zj,
                                                   unsigned char* __restrict__ zn,
                                                   float* __restrict__ sumexp) {
  int tid = threadIdx.x;
  int gid = blockIdx.x * 256 + tid;
  if (gid < NROWS) sumexp[gid] = 0.0f;
  int wave = tid >> 6, lane = tid & 63;
  int row = blockIdx.x * 4 + wave;
  const float* src = (row < HALF_N) ? (zi + (size_t)row * DIM)
                                    : (zj + (size_t)(row - HALF_N) * DIM);
  const float4* s4 = (const float4*)src;
  float4 a = s4[lane];        // cols 4*lane .. +3
  float4 b = s4[lane + 64];   // cols 256+4*lane .. +3
  float ss = a.x * a.x + a.y * a.y + a.z * a.z + a.w * a.w +
             b.x * b.x + b.y * b.y + b.z * b.z + b.w * b.w;
#pragma unroll
  for (int off = 32; off > 0; off >>= 1) ss += __shfl_xor(ss, off, 64);
  float inv = 1.0f / fmaxf(sqrtf(ss), 1e-8f);
  int w0 = __builtin_amdgcn_cvt_pk_fp8_f32(a.x * inv, a.y * inv, 0, false);
  w0 = __builtin_amdgcn_cvt_pk_fp8_f32(a.z * inv, a.w * inv, w0, true);
  int w1 = __builtin_amdgcn_cvt_pk_fp8_f32(b.x * inv, b.y * inv, 0, false);
  w1 = __builtin_amdgcn_cvt_pk_fp8_f32(b.z * inv, b.w * inv, w1, true);
  unsigned char* dst = zn + (size_t)row * DIM;
  *((int*)(dst + lane * 4)) = w0;
  *((int*)(dst + 256 + lane * 4)) = w1;
}

// R4: 256x256 upper-triangular tiles (528 blocks, 512 threads, 8 waves in a 2x4 grid;
// wave owns 128x64). Per window (BK=64): 64 MFMA/block -> ~1100 cy of MFMA per SIMD,
// long enough to cover global_load_lds latency at the SAME depth-2/vmcnt(4) ladder
// proven in R2 (4 loads/thread/window, identical counts). Staging traffic halves
// (2x arithmetic intensity); fill/epilogue events drop 2080 -> 528.
// R2->R3 lesson: don't buy in-block depth with occupancy; here occupancy is VGPR-pinned
// (acc[4][2]=128 AGPR + ~100 VGPR -> 8 waves/CU) so LDS 96 KB is free.
__global__ void __launch_bounds__(512, 2) k_simsum(const unsigned char* __restrict__ zn,
                                                   float* __restrict__ sumexp,
                                                   float* __restrict__ posv) {
  __shared__ __align__(16) unsigned char As[3][256 * 64];  // 3 x 16 KB
  __shared__ __align__(16) unsigned char Bs[3][256 * 64];  // 3 x 16 KB
  int tid = threadIdx.x;
  int wave = tid >> 6, lane = tid & 63;

  // XCD-aware bijective swizzle (528 = 8*66): consecutive idx share tn (B-panel).
  int bswz = (blockIdx.x & (NXCD - 1)) * TPX + (blockIdx.x >> 3);
  // triangular decode, tn-major: idx = tn(tn+1)/2 + tm, tm <= tn, tn in [0,32)
  int idx = bswz;
  int tn = (int)((sqrtf(8.0f * idx + 1.0f) - 1.0f) * 0.5f);
  while (tn * (tn + 1) / 2 > idx) tn--;
  while ((tn + 1) * (tn + 2) / 2 <= idx) tn++;
  int tm = idx - tn * (tn + 1) / 2;
  int rowBase = tm * 256, colBase = tn * 256;
  int wr = (wave >> 2) * 128, wc = (wave & 3) * 64;  // wave's 128x64 region
  int h = lane >> 5, c32 = lane & 31;                // k-half and row/col within 32-block

  // staging: wave stages 32 rows of A and B per window; 16B/lane; 4 lanes per 64-B row.
  // Physical granule p of row r holds source k-chunk p ^ ((r>>1)&3).
  int rA = wave * 32 + (lane >> 2);
  int chunk = (lane & 3) ^ ((rA >> 1) & 3);
  const unsigned char* gA = zn + (size_t)(rowBase + rA) * DIM + chunk * 16;
  const unsigned char* gB = zn + (size_t)(colBase + rA) * DIM + chunk * 16;

#define STAGE(b)                                            \
  do {                                                      \
    gload_lds16(gA, &As[b][wave * 2048]);                   \
    gload_lds16(gA + 16 * DIM, &As[b][wave * 2048 + 1024]); \
    gload_lds16(gB, &Bs[b][wave * 2048]);                   \
    gload_lds16(gB + 16 * DIM, &Bs[b][wave * 2048 + 1024]); \
    gA += 64; gB += 64;                                     \
  } while (0)

  f32x16 acc[4][2];
#pragma unroll
  for (int i = 0; i < 4; i++)
#pragma unroll
    for (int j = 0; j < 2; j++)
#pragma unroll
      for (int r = 0; r < 16; r++) acc[i][j][r] = 0.f;

  // Fragment read indices (int4 = one 16-B granule; row r at granule r*4).
  // Lane (c32,h) needs row-bytes k = h*32 + 0..31 -> granules 2h, 2h+1, XOR-swizzled.
  // sg invariant to wr (mult of 128) and i*32: sg = ((row>>1)&3) == ((c32>>1)&3).
  int sg = (c32 >> 1) & 3;
  int p0 = (2 * h) ^ sg, p1 = p0 ^ 1;
  int aIdx[4] = {(wr + c32) * 4, (wr + 32 + c32) * 4,
                 (wr + 64 + c32) * 4, (wr + 96 + c32) * 4};
  int bIdx[2] = {(wc + c32) * 4, (wc + 32 + c32) * 4};

#define COMPUTE(b)                                                                   \
  do {                                                                               \
    const int4* Av = (const int4*)As[b];                                             \
    const int4* Bv = (const int4*)Bs[b];                                             \
    i32x8 af[4], bfr[2];                                                             \
    _Pragma("unroll") for (int i = 0; i < 4; i++) {                                  \
      int4 lo = Av[aIdx[i] + p0], hi = Av[aIdx[i] + p1];                             \
      af[i] = (i32x8){lo.x, lo.y, lo.z, lo.w, hi.x, hi.y, hi.z, hi.w};               \
    }                                                                                \
    _Pragma("unroll") for (int j = 0; j < 2; j++) {                                  \
      int4 lo = Bv[bIdx[j] + p0], hi = Bv[bIdx[j] + p1];                             \
      bfr[j] = (i32x8){lo.x, lo.y, lo.z, lo.w, hi.x, hi.y, hi.z, hi.w};              \
    }                                                                                \
    __builtin_amdgcn_s_setprio(1);                                                   \
    _Pragma("unroll") for (int i = 0; i < 4; i++)                                    \
      _Pragma("unroll") for (int j = 0; j < 2; j++)                                  \
        acc[i][j] = __builtin_amdgcn_mfma_scale_f32_32x32x64_f8f6f4(                 \
            af[i], bfr[j], acc[i][j], 0, 0, /*fp8,fp8*/                              \
            0, 0x7F, 0, 0x7F);            /* scales = 2^0 */                         \
    __builtin_amdgcn_s_setprio(0);                                                   \
  } while (0)

  // ---- K loop: 3 buffers, depth-2 prefetch, counted vmcnt (R2's proven ladder). ----
  // Window s in buffer s%3. At iter-s entry: outstanding = w_s(4)+w_{s+1}(4);
  // vmcnt(4) completes w_s while w_{s+1} stays in flight. STAGE(w_{s+2}) overwrites
  // w_{s-1}, whose readers drained lgkmcnt before this iter's barrier.
#define ASM_VMCNT(n) asm volatile("s_waitcnt vmcnt(" #n ")" ::: "memory")
#define WINDOW(s, vm)                                        \
  do {                                                       \
    ASM_VMCNT(vm);                                           \
    asm volatile("s_waitcnt lgkmcnt(0)" ::: "memory");       \
    __builtin_amdgcn_sched_barrier(0);                       \
    __builtin_amdgcn_s_barrier();                            \
    __builtin_amdgcn_sched_barrier(0);                       \
    if ((s) + 2 < 8) STAGE(((s) + 2) % 3);                   \
    COMPUTE((s) % 3);                                        \
  } while (0)

  STAGE(0);  // w0
  STAGE(1);  // w1
  WINDOW(0, 4);
  WINDOW(1, 4);
  WINDOW(2, 4);
  WINDOW(3, 4);
  WINDOW(4, 4);
  WINDOW(5, 4);
  WINDOW(6, 4);
  WINDOW(7, 0);

  // ---- Epilogue. 32x32 C/D layout: col = lane&31, row = (reg&3)+8*(reg>>2)+4*h. ----
  // Wave's (i,j) cell holds rows wr+i*32, cols wc+j*32. Diagonal/positive cells are
  // where global row == global col (pos tiles have colBase = rowBase + 4096):
  // j == i - dj with dj = (wc - wr)/32 in {0,2,4,6,-4,-2}; only dj in {0,2} hit.
  bool isDiag = (tm == tn);
  bool hasPos = (tn == tm + 16);
  bool diagLane = (h == ((c32 >> 2) & 1));  // lane holding row==col elems of a 32x32
  int rsel = (c32 & 3) | ((c32 >> 3) << 2); // reg with rowIn32 == c32
  int dj = 2 * (wave & 3) - 4 * (wave >> 2);

  if (diagLane) {
    if (isDiag) {
      if (dj == 0) { acc[0][0][rsel] = -1e30f; acc[1][1][rsel] = -1e30f; }
      else if (dj == 2) { acc[2][0][rsel] = -1e30f; acc[3][1][rsel] = -1e30f; }
    }
    if (hasPos) {
      if (dj == 0) {
        int gr = rowBase + wr + c32;
        float s0 = acc[0][0][rsel] * INV_TEMP, s1 = acc[1][1][rsel] * INV_TEMP;
        posv[gr] = s0; posv[gr + HALF_N] = s0;           // unique (row,col) -> race-free
        posv[gr + 32] = s1; posv[gr + 32 + HALF_N] = s1; // sim symmetric
      } else if (dj == 2) {
        int gr = rowBase + wr + 64 + c32;
        float s0 = acc[2][0][rsel] * INV_TEMP, s1 = acc[3][1][rsel] * INV_TEMP;
        posv[gr] = s0; posv[gr + HALF_N] = s0;
        posv[gr + 32] = s1; posv[gr + 32 + HALF_N] = s1;
      }
    }
  }

  // exp2 + row-partials IN PLACE: acc[i][0][r] <- e0+e1; cp[j] = col partials.
  float cp[2] = {0.f, 0.f};
#pragma unroll
  for (int i = 0; i < 4; i++)
#pragma unroll
    for (int r = 0; r < 16; r++) {
      float e0 = __builtin_amdgcn_exp2f(acc[i][0][r] * E2SCALE);
      float e1 = __builtin_amdgcn_exp2f(acc[i][1][r] * E2SCALE);
      cp[0] += e0;
      cp[1] += e1;
      acc[i][0][r] = e0 + e1;
    }

  // Fold-reduce 32 row-partials across the 32-lane half; lane ends with value for
  // index c32 -> (i = c32>>4 within the pair, reg = c32&15).
#define FOLD5(RPX)                                                 \
  do {                                                             \
    _Pragma("unroll") for (int t = 0; t < 16; t++) {               \
      float mine = (lane & 16) ? RPX(t + 16) : RPX(t);             \
      float oth = __shfl_xor((lane & 16) ? RPX(t) : RPX(t + 16), 16, 64); \
      RPX(t) = mine + oth;                                         \
    }                                                              \
    _Pragma("unroll") for (int t = 0; t < 8; t++) {                \
      float mine = (lane & 8) ? RPX(t + 8) : RPX(t);               \
      float oth = __shfl_xor((lane & 8) ? RPX(t) : RPX(t + 8), 8, 64); \
      RPX(t) = mine + oth;                                         \
    }                                                              \
    _Pragma("unroll") for (int t = 0; t < 4; t++) {                \
      float mine = (lane & 4) ? RPX(t + 4) : RPX(t);               \
      float oth = __shfl_xor((lane & 4) ? RPX(t) : RPX(t + 4), 4, 64); \
      RPX(t) = mine + oth;                                         \
    }                                                              \
    _Pragma("unroll") for (int t = 0; t < 2; t++) {                \
      float mine = (lane & 2) ? RPX(t + 2) : RPX(t);               \
      float oth = __shfl_xor((lane & 2) ? RPX(t) : RPX(t + 2), 2, 64); \
      RPX(t) = mine + oth;                                         \
    }                                                              \
    {                                                              \
      float mine = (lane & 1) ? RPX(1) : RPX(0);                   \
      float oth = __shfl_xor((lane & 1) ? RPX(0) : RPX(1), 1, 64); \
      RPX(0) = mine + oth;                                         \
    }                                                              \
  } while (0)

#define RPA(t) acc[(t) >> 4][0][(t) & 15]
#define RPB(t) acc[2 + ((t) >> 4)][0][(t) & 15]
  // lane's row: (c32&3) + 8*((c32>>2)&3) + 4*h within 32; block 32*(c32>>4).
  int myrow = rowBase + wr + 32 * (c32 >> 4) + (c32 & 3) + 8 * ((c32 >> 2) & 3) + 4 * h;
  FOLD5(RPA);                               // i-tiles 0,1: rows wr .. wr+63
  atomicAdd(&sumexp[myrow], RPA(0));
  FOLD5(RPB);                               // i-tiles 2,3: rows wr+64 .. wr+127
  atomicAdd(&sumexp[myrow + 64], RPB(0));
#undef RPA
#undef RPB

  if (!isDiag) {
    // col sums: combine the two k-halves' rows, then lane-half h picks col-block j=h
    cp[0] += __shfl_xor(cp[0], 32, 64);
    cp[1] += __shfl_xor(cp[1], 32, 64);
    float cv = h ? cp[1] : cp[0];
    atomicAdd(&sumexp[colBase + wc + h * 32 + c32], cv);
  }
#undef STAGE
#undef COMPUTE
#undef WINDOW
#undef ASM_VMCNT
#undef FOLD5
}

__global__ void __launch_bounds__(1024) k_final(const float* __restrict__ sumexp,
                                                const float* __restrict__ posv,
                                                float* __restrict__ out) {
  __shared__ float red[16];
  int tid = threadIdx.x;
  const float4* se4 = (const float4*)sumexp;
  const float4* pv4 = (const float4*)posv;
  float p = 0.f;
#pragma unroll
  for (int c = 0; c < 2; c++) {
    float4 se = se4[tid * 2 + c];
    float4 pv = pv4[tid * 2 + c];
    p += (__builtin_amdgcn_logf(se.x) + __builtin_amdgcn_logf(se.y) +
          __builtin_amdgcn_logf(se.z) + __builtin_amdgcn_logf(se.w)) * LN2 -
         (pv.x + pv.y + pv.z + pv.w);
  }
#pragma unroll
  for (int off = 32; off > 0; off >>= 1) p += __shfl_xor(p, off, 64);
  int wv = tid >> 6, ln = tid & 63;
  if (ln == 0) red[wv] = p;
  __syncthreads();
  if (tid == 0) {
    float t = 0.f;
    for (int w = 0; w < 16; w++) t += red[w];
    out[0] = t / (float)NROWS;
  }
}

extern "C" void kernel_launch(void* const* d_in, const int* in_sizes, int n_in,
                              void* d_out, int out_size, void* d_ws, size_t ws_size,
                              hipStream_t stream) {
  const float* zi = (const float*)d_in[0];
  const float* zj = (const float*)d_in[1];
  unsigned char* zn = (unsigned char*)d_ws;                           // 4 MB fp8
  float* sumexp = (float*)((char*)d_ws + (size_t)NROWS * DIM);        // 32 KB
  float* posv = sumexp + NROWS;                                       // 32 KB
  float* out = (float*)d_out;

  hipLaunchKernelGGL(k_normalize, dim3(2048), dim3(256), 0, stream, zi, zj, zn, sumexp);
  hipLaunchKernelGGL(k_simsum, dim3(NTILES), dim3(512), 0, stream, zn, sumexp, posv);
  hipLaunchKernelGGL(k_final, dim3(1), dim3(1024), 0, stream, sumexp, posv, out);
}

// Round 5
// 94.576 us; speedup vs baseline: 1.0372x; 1.0372x over previous
//
#include <hip/hip_runtime.h>
#include <stdint.h>

#define NROWS 8192
#define HALF_N 4096
#define DIM 512          /* elements per row; == bytes per row in fp8 */
#define INV_TEMP 2.0f
#define E2SCALE 2.8853900817779268f  /* INV_TEMP * log2(e) */
#define LN2 0.6931471805599453f
#define NT128 2080       /* 128x128 upper-tri tiles: 64*65/2 */
#define GRID 768         /* 3 blocks/CU exactly; blocks own 2-3 tiles statically */
#define NXCD 8
#define TPX (GRID / NXCD)  /* 96; GRID % 8 == 0 -> bijective XCD swizzle */

typedef int i32x8 __attribute__((ext_vector_type(8)));
typedef float f32x16 __attribute__((ext_vector_type(16)));

// global -> LDS direct copy, 16B per lane; LDS dest is wave-uniform base + lane*16
__device__ __forceinline__ void gload_lds16(const unsigned char* g, unsigned char* l) {
  __builtin_amdgcn_global_load_lds(
      (const __attribute__((address_space(1))) unsigned int*)(uintptr_t)g,
      (__attribute__((address_space(3))) unsigned int*)(uint32_t)(uintptr_t)l,
      16, 0, 0);
}

// One wave per row: sumsq -> rsqrt -> fp8 e4m3 store (4 MB). Zeroes sumexp.
__global__ void __launch_bounds__(256) k_normalize(const float* __restrict__ zi,
                                                   const float* __restrict__ zj,
                                                   unsigned char* __restrict__ zn,
                                                   float* __restrict__ sumexp) {
  int tid = threadIdx.x;
  int gid = blockIdx.x * 256 + tid;
  if (gid < NROWS) sumexp[gid] = 0.0f;
  int wave = tid >> 6, lane = tid & 63;
  int row = blockIdx.x * 4 + wave;
  const float* src = (row < HALF_N) ? (zi + (size_t)row * DIM)
                                    : (zj + (size_t)(row - HALF_N) * DIM);
  const float4* s4 = (const float4*)src;
  float4 a = s4[lane];        // cols 4*lane .. +3
  float4 b = s4[lane + 64];   // cols 256+4*lane .. +3
  float ss = a.x * a.x + a.y * a.y + a.z * a.z + a.w * a.w +
             b.x * b.x + b.y * b.y + b.z * b.z + b.w * b.w;
#pragma unroll
  for (int off = 32; off > 0; off >>= 1) ss += __shfl_xor(ss, off, 64);
  float inv = 1.0f / fmaxf(sqrtf(ss), 1e-8f);
  int w0 = __builtin_amdgcn_cvt_pk_fp8_f32(a.x * inv, a.y * inv, 0, false);
  w0 = __builtin_amdgcn_cvt_pk_fp8_f32(a.z * inv, a.w * inv, w0, true);
  int w1 = __builtin_amdgcn_cvt_pk_fp8_f32(b.x * inv, b.y * inv, 0, false);
  w1 = __builtin_amdgcn_cvt_pk_fp8_f32(b.z * inv, b.w * inv, w1, true);
  unsigned char* dst = zn + (size_t)row * DIM;
  *((int*)(dst + lane * 4)) = w0;
  *((int*)(dst + 256 + lane * 4)) = w1;
}

// Epilogue for one 128x128 tile: diag mask, positives, exp2, row/col sums, acc re-zero.
// Identical math to R2's proven epilogue; rowBase=tm*128, colBase=tn*128.
__device__ __forceinline__ void epilogue(f32x16 (&acc)[2][2], int tm, int tn,
                                         int wave, int lane,
                                         float* __restrict__ sumexp,
                                         float* __restrict__ posv) {
  int wr = (wave >> 1) * 64, wc = (wave & 1) * 64;
  int h = lane >> 5, c32 = lane & 31;
  int rowBase = tm * 128, colBase = tn * 128;
  bool isDiag = (tm == tn);
  bool hasPos = (tn == tm + 32);
  bool diagLane = (wr == wc) && (h == ((c32 >> 2) & 1));
  int rsel = (c32 & 3) | ((c32 >> 3) << 2);

  if (isDiag && diagLane) {
    acc[0][0][rsel] = -1e30f;  // exp2 -> 0 (mask diagonal)
    acc[1][1][rsel] = -1e30f;
  }
  if (hasPos && diagLane) {
#pragma unroll
    for (int i = 0; i < 2; i++) {
      float sv = acc[i][i][rsel] * INV_TEMP;
      int gr = rowBase + wr + i * 32 + c32;
      posv[gr] = sv;            // unique (row,col) across grid -> race-free plain store
      posv[gr + HALF_N] = sv;   // sim symmetric
    }
  }

  float cp[2] = {0.f, 0.f};
#pragma unroll
  for (int i = 0; i < 2; i++)
#pragma unroll
    for (int r = 0; r < 16; r++) {
      float e0 = __builtin_amdgcn_exp2f(acc[i][0][r] * E2SCALE);
      float e1 = __builtin_amdgcn_exp2f(acc[i][1][r] * E2SCALE);
      cp[0] += e0;
      cp[1] += e1;
      acc[i][0][r] = e0 + e1;
    }

#define RP(t) acc[(t) >> 4][0][(t) & 15]
#pragma unroll
  for (int t = 0; t < 16; t++) {
    float mine = (lane & 16) ? RP(t + 16) : RP(t);
    float oth = __shfl_xor((lane & 16) ? RP(t) : RP(t + 16), 16, 64);
    RP(t) = mine + oth;
  }
#pragma unroll
  for (int t = 0; t < 8; t++) {
    float mine = (lane & 8) ? RP(t + 8) : RP(t);
    float oth = __shfl_xor((lane & 8) ? RP(t) : RP(t + 8), 8, 64);
    RP(t) = mine + oth;
  }
#pragma unroll
  for (int t = 0; t < 4; t++) {
    float mine = (lane & 4) ? RP(t + 4) : RP(t);
    float oth = __shfl_xor((lane & 4) ? RP(t) : RP(t + 4), 4, 64);
    RP(t) = mine + oth;
  }
#pragma unroll
  for (int t = 0; t < 2; t++) {
    float mine = (lane & 2) ? RP(t + 2) : RP(t);
    float oth = __shfl_xor((lane & 2) ? RP(t) : RP(t + 2), 2, 64);
    RP(t) = mine + oth;
  }
  {
    float mine = (lane & 1) ? RP(1) : RP(0);
    float oth = __shfl_xor((lane & 1) ? RP(0) : RP(1), 1, 64);
    RP(0) = mine + oth;
  }
  int myrow = rowBase + wr + 32 * (c32 >> 4) + (c32 & 3) + 8 * ((c32 >> 2) & 3) + 4 * h;
  atomicAdd(&sumexp[myrow], RP(0));
#undef RP

  if (!isDiag) {
    cp[0] += __shfl_xor(cp[0], 32, 64);
    cp[1] += __shfl_xor(cp[1], 32, 64);
    float cv = h ? cp[1] : cp[0];
    atomicAdd(&sumexp[colBase + wc + h * 32 + c32], cv);
  }

  // re-zero accumulator for the next tile
#pragma unroll
  for (int i = 0; i < 2; i++)
#pragma unroll
    for (int j = 0; j < 2; j++)
#pragma unroll
      for (int r = 0; r < 16; r++) acc[i][j][r] = 0.f;
}

// R5: PERSISTENT tiles. 768 blocks (3/CU), each statically owns tiles
// {t0, t0+768, t0+1536?} (t0 = XCD-swizzled blockIdx). The 3-buffer/depth-2/vmcnt
// ladder (proven R2) runs CONTINUOUSLY across tiles: at tile t's windows 6-7 the
// staging cursor jumps to tile t+1's rows, so the pipeline never drains between
// tiles; the epilogue (register-only) overlaps tile t+1's in-flight w0/w1 loads.
// vmcnt bookkeeping at tile boundaries: the epilogue's 2 atomicAdds (+0-2 posv
// stores) enter the per-wave vmcnt queue YOUNGER than next-tile w0/w1 but OLDER
// than w2..: steady tiles use vmcnt(6) at w0/w1 (retires the compute window
// without waiting on the slow LLC atomics), vmcnt(4) from w2 (atomics ~2.5
// windows old by then). First tile: plain (4,4). Last tile: w6=4, w7=0.
__global__ void __launch_bounds__(256, 3) k_simsum(const unsigned char* __restrict__ zn,
                                                   float* __restrict__ sumexp,
                                                   float* __restrict__ posv) {
  __shared__ __align__(16) unsigned char As[3 * 128 * 64];  // 24 KB
  __shared__ __align__(16) unsigned char Bs[3 * 128 * 64];  // 24 KB
  int tid = threadIdx.x;
  int wave = tid >> 6, lane = tid & 63;

  // Static tile list: t0 XCD-swizzled (768 = 8*96, bijective), +GRID, +2*GRID.
  int b = blockIdx.x;
  int t0 = (b & (NXCD - 1)) * TPX + (b >> 3);
  int t1 = t0 + GRID;                      // always < 2080 (t0 < 768)
  bool has3 = (t0 < NT128 - 2 * GRID);     // t0 < 544
  int t2 = t0 + 2 * GRID;

#define DECODE(idx, TM, TN)                                   \
  do {                                                        \
    int tn_ = (int)((sqrtf(8.0f * (idx) + 1.0f) - 1.0f) * 0.5f); \
    while (tn_ * (tn_ + 1) / 2 > (idx)) tn_--;                \
    while ((tn_ + 1) * (tn_ + 2) / 2 <= (idx)) tn_++;         \
    TN = tn_; TM = (idx)-tn_ * (tn_ + 1) / 2;                 \
  } while (0)

  int tm0, tn0, tm1, tn1, tm2 = 0, tn2 = 0;
  DECODE(t0, tm0, tn0);
  DECODE(t1, tm1, tn1);
  if (has3) DECODE(t2, tm2, tn2);

  int h = lane >> 5, c32 = lane & 31;

  // staging geometry (tile-invariant): wave stages 32 rows of A and B per window;
  // 16B/lane; 4 lanes per 64-B row. Granule p of row r holds k-chunk p ^ ((r>>1)&3).
  int rA = wave * 32 + (lane >> 2);
  int chunk = (lane & 3) ^ ((rA >> 1) & 3);
  const unsigned char* gA = zn + (size_t)(tm0 * 128 + rA) * DIM + chunk * 16;
  const unsigned char* gB = zn + (size_t)(tn0 * 128 + rA) * DIM + chunk * 16;

  // rotating buffer byte-offsets (straight-line code -> constant-folded):
  int oC = 0, oM = 8192, oS = 16384;
#define ROTATE() do { int t_ = oC; oC = oM; oM = oS; oS = t_; } while (0)

#define STAGE_AT(off)                                             \
  do {                                                            \
    unsigned char* la = As + (off) + wave * 2048;                 \
    unsigned char* lb = Bs + (off) + wave * 2048;                 \
    gload_lds16(gA, la);                                          \
    gload_lds16(gA + 16 * DIM, la + 1024);                        \
    gload_lds16(gB, lb);                                          \
    gload_lds16(gB + 16 * DIM, lb + 1024);                        \
    gA += 64; gB += 64;                                           \
  } while (0)

  f32x16 acc[2][2];
#pragma unroll
  for (int i = 0; i < 2; i++)
#pragma unroll
    for (int j = 0; j < 2; j++)
#pragma unroll
      for (int r = 0; r < 16; r++) acc[i][j][r] = 0.f;

  // Fragment read indices (int4 = one 16-B granule; row r at granule r*4).
  int wr = (wave >> 1) * 64, wc = (wave & 1) * 64;
  int sg = (c32 >> 1) & 3;
  int p0 = (2 * h) ^ sg, p1 = p0 ^ 1;
  int aIdx[2] = {(wr + c32) * 4, (wr + 32 + c32) * 4};
  int bIdx[2] = {(wc + c32) * 4, (wc + 32 + c32) * 4};

#define COMPUTE()                                                                    \
  do {                                                                               \
    const int4* Av = (const int4*)(As + oC);                                         \
    const int4* Bv = (const int4*)(Bs + oC);                                         \
    i32x8 af[2], bfr[2];                                                             \
    _Pragma("unroll") for (int i = 0; i < 2; i++) {                                  \
      int4 lo = Av[aIdx[i] + p0], hi = Av[aIdx[i] + p1];                             \
      af[i] = (i32x8){lo.x, lo.y, lo.z, lo.w, hi.x, hi.y, hi.z, hi.w};               \
    }                                                                                \
    _Pragma("unroll") for (int j = 0; j < 2; j++) {                                  \
      int4 lo = Bv[bIdx[j] + p0], hi = Bv[bIdx[j] + p1];                             \
      bfr[j] = (i32x8){lo.x, lo.y, lo.z, lo.w, hi.x, hi.y, hi.z, hi.w};              \
    }                                                                                \
    __builtin_amdgcn_s_setprio(1);                                                   \
    _Pragma("unroll") for (int i = 0; i < 2; i++)                                    \
      _Pragma("unroll") for (int j = 0; j < 2; j++)                                  \
        acc[i][j] = __builtin_amdgcn_mfma_scale_f32_32x32x64_f8f6f4(                 \
            af[i], bfr[j], acc[i][j], 0, 0, /*fp8,fp8*/                              \
            0, 0x7F, 0, 0x7F);            /* scales = 2^0 */                         \
    __builtin_amdgcn_s_setprio(0);                                                   \
  } while (0)

#define ASM_VMCNT(n) asm volatile("s_waitcnt vmcnt(" #n ")" ::: "memory")
#define SYNC(vm)                                             \
  do {                                                       \
    ASM_VMCNT(vm);                                           \
    asm volatile("s_waitcnt lgkmcnt(0)" ::: "memory");       \
    __builtin_amdgcn_sched_barrier(0);                       \
    __builtin_amdgcn_s_barrier();                            \
    __builtin_amdgcn_sched_barrier(0);                       \
  } while (0)

#define WINDOW_N(vm)  do { SYNC(vm); STAGE_AT(oS); COMPUTE(); ROTATE(); } while (0)
#define WINDOW_NOSTAGE(vm) do { SYNC(vm); COMPUTE(); ROTATE(); } while (0)

  // w0..w5 of a tile (stage current-tile windows 2..7):
#define TILE_HEAD(v0, v1)                                       \
  do { WINDOW_N(v0); WINDOW_N(v1); WINDOW_N(4); WINDOW_N(4);    \
       WINDOW_N(4); WINDOW_N(4); } while (0)
  // w6,w7 staging NEXT tile's w0,w1 (cursor jump keeps the pipeline full):
#define TILE_TAIL_NEXT(nTm, nTn)                                        \
  do {                                                                  \
    SYNC(4);                                                            \
    gA = zn + (size_t)((nTm) * 128 + rA) * DIM + chunk * 16;            \
    gB = zn + (size_t)((nTn) * 128 + rA) * DIM + chunk * 16;            \
    STAGE_AT(oS); COMPUTE(); ROTATE();                                  \
    SYNC(4); STAGE_AT(oS); COMPUTE(); ROTATE();                         \
  } while (0)
#define TILE_TAIL_LAST() do { WINDOW_NOSTAGE(4); WINDOW_NOSTAGE(0); } while (0)

  // prologue: tile0 windows 0,1
  STAGE_AT(0);
  STAGE_AT(8192);

  // tile0 (first: no prior epilogue ops in the vmcnt queue -> plain 4,4 ladder)
  TILE_HEAD(4, 4);
  TILE_TAIL_NEXT(tm1, tn1);
  epilogue(acc, tm0, tn0, wave, lane, sumexp, posv);

  // tile1 head (steady: 6,6 skips the epilogue atomics in the queue)
  TILE_HEAD(6, 6);
  if (has3) {
    TILE_TAIL_NEXT(tm2, tn2);
    epilogue(acc, tm1, tn1, wave, lane, sumexp, posv);
    TILE_HEAD(6, 6);
    TILE_TAIL_LAST();
    epilogue(acc, tm2, tn2, wave, lane, sumexp, posv);
  } else {
    TILE_TAIL_LAST();
    epilogue(acc, tm1, tn1, wave, lane, sumexp, posv);
  }
#undef DECODE
#undef ROTATE
#undef STAGE_AT
#undef COMPUTE
#undef ASM_VMCNT
#undef SYNC
#undef WINDOW_N
#undef WINDOW_NOSTAGE
#undef TILE_HEAD
#undef TILE_TAIL_NEXT
#undef TILE_TAIL_LAST
}

__global__ void __launch_bounds__(1024) k_final(const float* __restrict__ sumexp,
                                                const float* __restrict__ posv,
                                                float* __restrict__ out) {
  __shared__ float red[16];
  int tid = threadIdx.x;
  const float4* se4 = (const float4*)sumexp;
  const float4* pv4 = (const float4*)posv;
  float p = 0.f;
#pragma unroll
  for (int c = 0; c < 2; c++) {
    float4 se = se4[tid * 2 + c];
    float4 pv = pv4[tid * 2 + c];
    p += (__builtin_amdgcn_logf(se.x) + __builtin_amdgcn_logf(se.y) +
          __builtin_amdgcn_logf(se.z) + __builtin_amdgcn_logf(se.w)) * LN2 -
         (pv.x + pv.y + pv.z + pv.w);
  }
#pragma unroll
  for (int off = 32; off > 0; off >>= 1) p += __shfl_xor(p, off, 64);
  int wv = tid >> 6, ln = tid & 63;
  if (ln == 0) red[wv] = p;
  __syncthreads();
  if (tid == 0) {
    float t = 0.f;
    for (int w = 0; w < 16; w++) t += red[w];
    out[0] = t / (float)NROWS;
  }
}

extern "C" void kernel_launch(void* const* d_in, const int* in_sizes, int n_in,
                              void* d_out, int out_size, void* d_ws, size_t ws_size,
                              hipStream_t stream) {
  const float* zi = (const float*)d_in[0];
  const float* zj = (const float*)d_in[1];
  unsigned char* zn = (unsigned char*)d_ws;                           // 4 MB fp8
  float* sumexp = (float*)((char*)d_ws + (size_t)NROWS * DIM);        // 32 KB
  float* posv = sumexp + NROWS;                                       // 32 KB
  float* out = (float*)d_out;

  hipLaunchKernelGGL(k_normalize, dim3(2048), dim3(256), 0, stream, zi, zj, zn, sumexp);
  hipLaunchKernelGGL(k_simsum, dim3(GRID), dim3(256), 0, stream, zn, sumexp, posv);
  hipLaunchKernelGGL(k_final, dim3(1), dim3(1024), 0, stream, sumexp, posv, out);
}